// Round 1
// 203.508 us; speedup vs baseline: 1.0234x; 1.0234x over previous
//
#include <hip/hip_runtime.h>
#include <math.h>

#define H 1024
#define S 32768
#define NPART 16          // d-partials for the W^T @ hidden matvec

// ws layout (floats):
//   [0, 16384)            partial[p][h]  p<16, h<1024
//   [16384, 49152)        scores [S]
//   [49152, 50176)        pm (per-block softmax max)
//   [50176, 51200)        ps (per-block softmax sumexp)
//   [51200, 52224)        v[H] = W^T @ hidden (final, reduced)
#define WS_PART   0
#define WS_SCORES 16384
#define WS_PM     (16384 + S)
#define WS_PS     (16384 + S + 1024)
#define WS_V      (16384 + S + 2048)

// ---------------------------------------------------------------------------
// K1: part[by][h] = sum_{d in by-chunk of 64} W[d][h] * hidden[d]
// grid (16, 16), block 256: bx = h-group of 64, by = d-chunk of 64.
// 256 blocks -> 4x the read parallelism of the old 64-block version.
// Thread (l, dg): h = bx*64+l, d-subchunk dg of 16; in-block LDS reduce over dg.
// ---------------------------------------------------------------------------
__global__ __launch_bounds__(256) void matvec_partial(const float* __restrict__ W,
                                                      const float* __restrict__ hidden,
                                                      float* __restrict__ ws) {
    float* part = ws + WS_PART;
    const int t  = threadIdx.x;
    const int l  = t & 63;          // h offset within group
    const int dg = t >> 6;          // d sub-chunk (0..3)
    const int h  = blockIdx.x * 64 + l;
    const int d0 = blockIdx.y * 64 + dg * 16;

    float acc = 0.f;
#pragma unroll
    for (int i = 0; i < 16; ++i) {
        const int d = d0 + i;
        acc += W[(size_t)d * H + h] * hidden[d];   // 256 B contiguous per (i,dg)
    }

    __shared__ float red[4][64];
    red[dg][l] = acc;
    __syncthreads();
    if (t < 64) {
        part[blockIdx.y * H + blockIdx.x * 64 + l] =
            red[0][l] + red[1][l] + red[2][l] + red[3][l];
    }
}

// ---------------------------------------------------------------------------
// K1b: v[h] = sum_p part[p][h]. Collapses the 16 partials ONCE (64 KB read)
// instead of once per K2 block (64 MiB aggregate L2 in the old version).
// grid 4 x 64 threads; each thread owns one float4 column.
// ---------------------------------------------------------------------------
__global__ __launch_bounds__(64) void reduce_v(float* __restrict__ ws) {
    const float* part = ws + WS_PART;
    float* v = ws + WS_V;
    const int i = blockIdx.x * 64 + threadIdx.x;   // float4 index < 256
    const float4* p4 = (const float4*)part;
    float4 a = p4[i];
#pragma unroll
    for (int p = 1; p < NPART; ++p) {
        const float4 w = p4[p * (H / 4) + i];
        a.x += w.x; a.y += w.y; a.z += w.z; a.w += w.w;
    }
    ((float4*)v)[i] = a;
}

// ---------------------------------------------------------------------------
// K2: per-row scores + per-block softmax partials.
// 1024 blocks x 256 threads; wave w of block b owns rows (b*4+w)*8 .. +8.
// No LDS, no __syncthreads: v-fragments come straight from L2 (v is 4 KB,
// broadcast-hot). All 8 row-dots accumulate first; shuffle butterflies leave
// the row-sum in every lane, so max/sumexp is one deferred parallel pass
// (no serial online-rescale chain between rows).
// ---------------------------------------------------------------------------
__global__ __launch_bounds__(256) void scores_partial(const float* __restrict__ enc,
                                                      float* __restrict__ ws) {
    float* scores = ws + WS_SCORES;
    float* pm     = ws + WS_PM;
    float* ps     = ws + WS_PS;
    const float* v = ws + WS_V;

    const int tid  = threadIdx.x;
    const int lane = tid & 63;
    const int wv   = tid >> 6;
    const int blk  = blockIdx.x;
    const int gw   = blk * 4 + wv;
    const size_t row0 = (size_t)gw * 8;

    const float4* v4 = (const float4*)v;
    float4 vf[4];
#pragma unroll
    for (int k = 0; k < 4; ++k) vf[k] = v4[lane + 64 * k];

    float a[8];
#pragma unroll
    for (int it = 0; it < 8; ++it) {
        const float4* e4 = (const float4*)(enc + (row0 + it) * H);
        const float4 e0 = e4[lane];
        const float4 e1 = e4[lane + 64];
        const float4 e2 = e4[lane + 128];
        const float4 e3 = e4[lane + 192];
        float s0 = e0.x * vf[0].x + e0.y * vf[0].y + e0.z * vf[0].z + e0.w * vf[0].w;
        float s1 = e1.x * vf[1].x + e1.y * vf[1].y + e1.z * vf[1].z + e1.w * vf[1].w;
        float s2 = e2.x * vf[2].x + e2.y * vf[2].y + e2.z * vf[2].z + e2.w * vf[2].w;
        float s3 = e3.x * vf[3].x + e3.y * vf[3].y + e3.z * vf[3].z + e3.w * vf[3].w;
        a[it] = (s0 + s1) + (s2 + s3);
    }

    // butterfly reduce each row; result lands in ALL lanes
#pragma unroll
    for (int it = 0; it < 8; ++it) {
#pragma unroll
        for (int off = 32; off > 0; off >>= 1)
            a[it] += __shfl_xor(a[it], off, 64);
        if (lane == 0) scores[row0 + it] = a[it];
    }

    // deferred wave-level softmax partial: fmax tree + 8 independent exps
    float m01 = fmaxf(a[0], a[1]), m23 = fmaxf(a[2], a[3]);
    float m45 = fmaxf(a[4], a[5]), m67 = fmaxf(a[6], a[7]);
    const float mw = fmaxf(fmaxf(m01, m23), fmaxf(m45, m67));
    float sw = 0.f;
#pragma unroll
    for (int it = 0; it < 8; ++it) sw += __expf(a[it] - mw);

    __shared__ float sm[4], ss[4];
    if (lane == 0) { sm[wv] = mw; ss[wv] = sw; }
    __syncthreads();
    if (tid == 0) {
        float m = sm[0], s = ss[0];
#pragma unroll
        for (int i = 1; i < 4; ++i) {
            const float nm = fmaxf(m, sm[i]);
            s = s * __expf(m - nm) + ss[i] * __expf(sm[i] - nm);
            m = nm;
        }
        pm[blk] = m; ps[blk] = s;
    }
}

// ---------------------------------------------------------------------------
// K3: every block redundantly combines the 1024 (m,s) pairs, then
// normalizes its 256 scores. grid 128 blocks x 256 threads.
// ---------------------------------------------------------------------------
__global__ __launch_bounds__(256) void finalize(const float* __restrict__ ws,
                                                float* __restrict__ out) {
    const float* scores = ws + WS_SCORES;
    const float* pm     = ws + WS_PM;
    const float* ps     = ws + WS_PS;

    const int tid  = threadIdx.x;
    const int lane = tid & 63;
    const int wv   = tid >> 6;

    float m = -INFINITY, s = 0.f;
#pragma unroll
    for (int i = 0; i < 4; ++i) {
        const int idx = tid + i * 256;
        const float om = pm[idx], os = ps[idx];
        const float nm = fmaxf(m, om);
        s = s * __expf(m - nm) + os * __expf(om - nm);
        m = nm;
    }
#pragma unroll
    for (int off = 32; off > 0; off >>= 1) {
        const float om = __shfl_xor(m, off, 64);
        const float os = __shfl_xor(s, off, 64);
        const float nm = fmaxf(m, om);
        s = s * __expf(m - nm) + os * __expf(om - nm);
        m = nm;
    }
    __shared__ float sm[4], ss[4];
    if (lane == 0) { sm[wv] = m; ss[wv] = s; }
    __syncthreads();
    float M = sm[0], Ssum = ss[0];
#pragma unroll
    for (int i = 1; i < 4; ++i) {
        const float nm = fmaxf(M, sm[i]);
        Ssum = Ssum * __expf(M - nm) + ss[i] * __expf(sm[i] - nm);
        M = nm;
    }
    const float rs = 1.0f / Ssum;

    const int i = blockIdx.x * 256 + tid;
    out[i] = __expf(scores[i] - M) * rs;
}

extern "C" void kernel_launch(void* const* d_in, const int* in_sizes, int n_in,
                              void* d_out, int out_size, void* d_ws, size_t ws_size,
                              hipStream_t stream) {
    const float* hidden = (const float*)d_in[0];   // [H]
    const float* enc    = (const float*)d_in[1];   // [S, H]
    const float* W      = (const float*)d_in[2];   // [H, H]
    // d_in[3] = b — unused: b·hidden is a uniform softmax shift (cancels exactly).
    float* out = (float*)d_out;                    // [S] fp32
    float* ws  = (float*)d_ws;

    matvec_partial<<<dim3(16, 16), 256, 0, stream>>>(W, hidden, ws);
    reduce_v<<<4, 64, 0, stream>>>(ws);
    scores_partial<<<1024, 256, 0, stream>>>(enc, ws);
    finalize<<<S / 256, 256, 0, stream>>>(ws, out);
}